// Round 1
// baseline (48120.639 us; speedup 1.0000x reference)
//
#include <hip/hip_runtime.h>
#include <hip/hip_bf16.h>

typedef unsigned short u16;
typedef __attribute__((ext_vector_type(8))) short short8;
typedef __attribute__((ext_vector_type(4))) float f32x4;

__device__ __forceinline__ float sigf(float x) { return 1.0f / (1.0f + __expf(-x)); }
__device__ __forceinline__ float tanhfast(float x) { return 2.0f / (1.0f + __expf(-2.0f * x)) - 1.0f; }
__device__ __forceinline__ u16 f2b(float f) {
    union { float f; unsigned u; } v; v.f = f;
    unsigned u = v.u;
    unsigned r = (u + 0x7FFFu + ((u >> 16) & 1u)) >> 16;
    return (u16)r;
}
__device__ __forceinline__ float b2f(u16 h) {
    union { unsigned u; float f; } v; v.u = ((unsigned)h) << 16;
    return v.f;
}

// ---------------------------------------------------------------- pack kernels
__global__ void k_pack(const float* Wih, int K_ih, int K_ih_pad, const float* Whh, int K_hh,
                       int N, u16* dst)
{
    int K = K_ih_pad + K_hh;
    int KT = K >> 5;
    long total = (long)(N >> 4) * KT * 64;
    long idx = (long)blockIdx.x * 256 + threadIdx.x;
    if (idx >= total) return;
    int lane = (int)(idx & 63);
    long t2 = idx >> 6;
    int kt = (int)(t2 % KT);
    long nt = t2 / KT;
    int n = (int)nt * 16 + (lane & 15);
    int kb = kt * 32 + ((lane >> 4) << 3);
    u16* dp = dst + idx * 8;
#pragma unroll
    for (int j = 0; j < 8; ++j) {
        int k = kb + j;
        float v;
        if (k < K_ih) v = Wih[(size_t)n * K_ih + k];
        else if (k < K_ih_pad) v = 0.0f;
        else v = Whh[(size_t)n * K_hh + (k - K_ih_pad)];
        dp[j] = f2b(v);
    }
}

__global__ void k_bias(const float* a1, const float* a2, const float* b1, const float* b2,
                       const float* c1, const float* c2, float* oB, float* oP, float* oT)
{
    int idx = blockIdx.x * 256 + threadIdx.x;
    if (idx < 8192) oB[idx] = a1[idx] + a2[idx];
    else if (idx < 16384) { int i = idx - 8192; oP[i] = b1[i] + b2[i]; }
    else if (idx < 18432) { int i = idx - 16384; oT[i] = c1[i] + c2[i]; }
}

// normalize coords -> ptraceF [t][1408][2] f32, rnn_in[t][b][0:44) bf16, zero pad [624:640)
__global__ void k_coords(const float* coords, float* ptraceF, u16* rnn_in)
{
    int idx = blockIdx.x * 256 + threadIdx.x;
    if (idx >= 200 * 64 * 38) return;
    int t = idx / (64 * 38);
    int rem = idx - t * (64 * 38);
    int b = rem / 38, s2 = rem - b * 38;
    if (s2 < 22) {
        int p = s2;
        float x = coords[((size_t)b * 200 + t) * 88 + 4 * p] * (1.0f / 105.0f);
        float y = coords[((size_t)b * 200 + t) * 88 + 4 * p + 1] * (1.0f / 68.0f);
        size_t r = (size_t)t * 1408 + b * 22 + p;
        ptraceF[r * 2] = x;
        ptraceF[r * 2 + 1] = y;
        u16* rp = rnn_in + ((size_t)t * 64 + b) * 640;
        rp[2 * p] = f2b(x);
        rp[2 * p + 1] = f2b(y);
    } else {
        int i = s2 - 22;
        rnn_in[((size_t)t * 64 + b) * 640 + 624 + i] = 0;
    }
}

// ---------------------------------------------------------------- set encoder
__global__ __launch_bounds__(256) void k_enc(const float* ptraceF,
    const float* w1, const float* b1, const float* w2, const float* b2,
    const float* w3, const float* b3, u16* rnn_in)
{
    __shared__ u16 w2s[128 * 128];
    __shared__ float w1s[256];
    __shared__ float b1s[128], b2s[128];
    __shared__ float h1s[2][11][128];
    __shared__ float ms[2][128];
    __shared__ float pts[2][11][2];
    const int tid = threadIdx.x;
    for (int i = tid; i < 16384; i += 256) w2s[i] = f2b(w2[i]);
    if (tid < 256) w1s[tid] = w1[tid];
    if (tid < 128) { b1s[tid] = b1[tid]; b2s[tid] = b2[tid]; }
    __syncthreads();
    const int set = tid >> 7, j = tid & 127;
    for (int it = 0; it < 8; ++it) {
        int tb = blockIdx.x * 8 + it;          // 0..12799
        int t = tb / 64, b = tb - t * 64;
        if (tid < 44) {
            int pp = tid >> 1, e = tid & 1;
            pts[pp / 11][pp % 11][e] = ptraceF[((size_t)t * 1408 + b * 22 + pp) * 2 + e];
        }
        __syncthreads();
        // h1
        float h1r[11];
#pragma unroll
        for (int p = 0; p < 11; ++p)
            h1r[p] = fmaxf(0.0f, pts[set][p][0] * w1s[j] + pts[set][p][1] * w1s[128 + j] + b1s[j]);
#pragma unroll
        for (int p = 0; p < 11; ++p) h1s[set][p][j] = h1r[p];
        __syncthreads();
        // h2 + mean
        float ac[11];
#pragma unroll
        for (int p = 0; p < 11; ++p) ac[p] = b2s[j];
        for (int k4 = 0; k4 < 128; k4 += 4) {
            float wv0 = b2f(w2s[(k4 + 0) * 128 + j]);
            float wv1 = b2f(w2s[(k4 + 1) * 128 + j]);
            float wv2 = b2f(w2s[(k4 + 2) * 128 + j]);
            float wv3 = b2f(w2s[(k4 + 3) * 128 + j]);
#pragma unroll
            for (int p = 0; p < 11; ++p) {
                const float4 h4 = *(const float4*)&h1s[set][p][k4];
                ac[p] += h4.x * wv0 + h4.y * wv1 + h4.z * wv2 + h4.w * wv3;
            }
        }
        float msum = 0.0f;
#pragma unroll
        for (int p = 0; p < 11; ++p) msum += fmaxf(0.0f, ac[p]);
        ms[set][j] = msum * (1.0f / 11.0f);
        __syncthreads();
        // out: 2 outputs per thread
        for (int jo = j; jo < 256; jo += 128) {
            float a = b3[jo];
            for (int k4 = 0; k4 < 128; k4 += 4) {
                const float4 m4 = *(const float4*)&ms[set][k4];
                a += m4.x * w3[(k4 + 0) * 256 + jo] + m4.y * w3[(k4 + 1) * 256 + jo]
                   + m4.z * w3[(k4 + 2) * 256 + jo] + m4.w * w3[(k4 + 3) * 256 + jo];
            }
            rnn_in[((size_t)t * 64 + b) * 640 + 44 + set * 256 + jo] = f2b(a);
        }
        __syncthreads();
    }
}

// ---------------------------------------------------------------- traj LSTM layer (one layer of one step for 16 rows)
struct TrajSmem {
    float xy[16][2];
    float h3[16][128];
    float pre[16][4];
};

__device__ void traj_layer(int l, int s, int r0,
    const u16* packT, const float* bcT, const float* wih0,
    const float* ptraceF, u16* hT, float* cT,
    u16* rnn_in, float* d_out, const float* lsw, const float* lsb,
    TrajSmem* sm)
{
    const int tid = threadIdx.x;
    const int w = tid >> 6, lane = tid & 63;
    const int quad = lane >> 4, col = lane & 15;
    const int KT = (l == 0) ? 4 : 8;
    const u16* pk = packT + ((l == 0) ? (size_t)0 : ((size_t)128 * 512 + (size_t)(l - 1) * 256 * 512));

    if (l == 0) {
        if (tid < 32) {
            int m = tid >> 1, e = tid & 1;
            sm->xy[m][e] = ptraceF[((size_t)s * 1408 + r0 + m) * 2 + e];
        }
    }
    __syncthreads();

    f32x4 acc[8];
#pragma unroll
    for (int i = 0; i < 8; ++i) {
        int n = (w + 4 * i) * 16 + col;
        float bb = bcT[l * 512 + n];
        if (l == 0) {
            float wx = wih0[n * 2], wy = wih0[n * 2 + 1];
#pragma unroll
            for (int r = 0; r < 4; ++r)
                acc[i][r] = bb + wx * sm->xy[quad * 4 + r][0] + wy * sm->xy[quad * 4 + r][1];
        } else {
#pragma unroll
            for (int r = 0; r < 4; ++r) acc[i][r] = bb;
        }
    }

    for (int kt = 0; kt < KT; ++kt) {
        const u16* ap;
        if (l == 0)
            ap = hT + ((size_t)r0 + col) * 128 + kt * 32 + quad * 8;
        else if (kt < 4)
            ap = hT + ((size_t)(l - 1) * 1408 + r0 + col) * 128 + kt * 32 + quad * 8;
        else
            ap = hT + ((size_t)l * 1408 + r0 + col) * 128 + (kt - 4) * 32 + quad * 8;
        short8 a8 = *(const short8*)ap;
#pragma unroll
        for (int i = 0; i < 8; ++i) {
            int nt = w + 4 * i;
            short8 b8 = *(const short8*)(pk + ((size_t)(nt * KT + kt) * 64 + lane) * 8);
            acc[i] = __builtin_amdgcn_mfma_f32_16x16x32_bf16(a8, b8, acc[i], 0, 0, 0);
        }
    }
    __syncthreads();   // all A reads of hT[l] complete before overwrite

    // in-register cell update: part = i>>1 (i,f,g,o), pair h = i&1
#pragma unroll
    for (int h = 0; h < 2; ++h) {
        int j = 64 * h + 16 * w + col;
#pragma unroll
        for (int r = 0; r < 4; ++r) {
            int m = quad * 4 + r;
            size_t ci = ((size_t)l * 1408 + r0 + m) * 128 + j;
            float c_old = cT[ci];
            float cn = sigf(acc[2 + h][r]) * c_old + sigf(acc[0 + h][r]) * tanhfast(acc[4 + h][r]);
            float hn = sigf(acc[6 + h][r]) * tanhfast(cn);
            cT[ci] = cn;
            hT[ci] = f2b(hn);
            if (l == 3) sm->h3[m][j] = hn;
        }
    }

    if (l == 3) {
        __syncthreads();
        if (tid < 64) {
            int m = tid >> 2, g = tid & 3;
            float a = lsb[g];
            const float* wr = lsw + g * 128;
#pragma unroll 8
            for (int k = 0; k < 128; ++k) a += sm->h3[m][k] * wr[k];
            sm->pre[m][g] = a;
        }
        __syncthreads();
        if (tid < 32) {
            int m = tid >> 1, e = tid & 1;
            float v = sm->pre[m][e] * sigf(sm->pre[m][2 + e]);
            int rr = r0 + m, b = rr / 22, p = rr - b * 22;
            rnn_in[((size_t)s * 64 + b) * 640 + 556 + 2 * p + e] = f2b(v);
            d_out[((size_t)b * 200 + s) * 46 + 2 * p + e] = v * (e ? 68.0f : 105.0f);
        }
        __syncthreads();
    } else {
        __syncthreads();
    }
}

__global__ __launch_bounds__(256) void k_traj0(const u16* packT, const float* bcT,
    const float* wih0, const float* ptraceF, u16* hT, float* cT,
    u16* rnn_in, float* d_out, const float* lsw, const float* lsb)
{
    __shared__ TrajSmem tsm;
    int r0 = blockIdx.x * 16;
    for (int l = 0; l < 4; ++l)
        traj_layer(l, 0, r0, packT, bcT, wih0, ptraceF, hT, cT, rnn_in, d_out, lsw, lsb, &tsm);
}

// ---------------------------------------------------------------- per-step layer kernel
// blocks 0..31 ball, 32..63 pos (layer l of step t); blocks 64..151 traj (layer l of step t+1)
__global__ __launch_bounds__(256) void k_step(int l, int t,
    const u16* rnn_in_r, u16* rnn_in_w,
    const u16* packB, const u16* packP, const u16* packT,
    const float* bcB, const float* bcP, const float* bcT,
    u16* hB, float* cB, u16* hP, float* cP, u16* hT, float* cT,
    const float* wih0T, const float* ptraceF,
    float* d_out, const float* lsw, const float* lsb)
{
    __shared__ float g_lds[64][65];
    __shared__ TrajSmem tsm;

    if (blockIdx.x >= 64) {
        int s = t + 1;
        if (s >= 200) return;
        int r0 = ((int)blockIdx.x - 64) * 16;
        traj_layer(l, s, r0, packT, bcT, wih0T, ptraceF, hT, cT, rnn_in_w, d_out, lsw, lsb, &tsm);
        return;
    }

    const int lstm = blockIdx.x >> 5;        // 0 ball, 1 pos
    const int B = blockIdx.x & 31;
    const u16* pack = lstm ? packP : packB;
    const float* bc = lstm ? bcP : bcB;
    u16* hbuf = lstm ? hP : hB;              // [2][4][64][512] bf16
    float* cbuf = lstm ? cP : cB;            // [4][64][512] f32
    const int tid = threadIdx.x, w = tid >> 6, lane = tid & 63;
    const int quad = lane >> 4, col = lane & 15;
    const int pr = t & 1, pw = 1 - pr;
    const int KT = (l == 0) ? 36 : 32;
    const u16* pk = pack
        + ((l == 0) ? (size_t)0 : ((size_t)1152 * 2048 + (size_t)(l - 1) * 1024 * 2048))
        + (size_t)(32 * w + B) * KT * 512;
    const float bias = bc[l * 2048 + 512 * w + 16 * B + col];
    f32x4 acc[4];
#pragma unroll
    for (int m = 0; m < 4; ++m) { acc[m][0] = bias; acc[m][1] = bias; acc[m][2] = bias; acc[m][3] = bias; }

    for (int kt = 0; kt < KT; ++kt) {
        short8 b8 = *(const short8*)(pk + (size_t)kt * 512 + lane * 8);
#pragma unroll
        for (int m = 0; m < 4; ++m) {
            int row = m * 16 + col;
            const u16* ap;
            if (l == 0) {
                if (kt < 20) ap = rnn_in_r + ((size_t)t * 64 + row) * 640 + kt * 32 + quad * 8;
                else ap = hbuf + (((size_t)pr * 4 + 0) * 64 + row) * 512 + (kt - 20) * 32 + quad * 8;
            } else {
                if (kt < 16) ap = hbuf + (((size_t)pw * 4 + (l - 1)) * 64 + row) * 512 + kt * 32 + quad * 8;
                else ap = hbuf + (((size_t)pr * 4 + l) * 64 + row) * 512 + (kt - 16) * 32 + quad * 8;
            }
            short8 a8 = *(const short8*)ap;
            acc[m] = __builtin_amdgcn_mfma_f32_16x16x32_bf16(a8, b8, acc[m], 0, 0, 0);
        }
    }
#pragma unroll
    for (int m = 0; m < 4; ++m)
#pragma unroll
        for (int r = 0; r < 4; ++r)
            g_lds[m * 16 + quad * 4 + r][w * 16 + col] = acc[m][r];
    __syncthreads();
    {
        int r = tid & 63;
        int jb = (tid >> 6) * 4;
#pragma unroll
        for (int q = 0; q < 4; ++q) {
            int jl = jb + q;
            float gi = g_lds[r][jl], gf = g_lds[r][16 + jl];
            float gg = g_lds[r][32 + jl], go = g_lds[r][48 + jl];
            size_t ci = ((size_t)l * 64 + r) * 512 + 16 * B + jl;
            float c_old = cbuf[ci];
            float cn = sigf(gf) * c_old + sigf(gi) * tanhfast(gg);
            float hn = sigf(go) * tanhfast(cn);
            cbuf[ci] = cn;
            hbuf[(((size_t)pw * 4 + l) * 64 + r) * 512 + 16 * B + jl] = f2b(hn);
        }
    }
}

// ---------------------------------------------------------------- glue: pred/new_step/pos_out, dists, rnn_in tail
__global__ __launch_bounds__(256) void k_glue(int t,
    const u16* hB, const u16* hP,
    const float* lin_w, const float* lin_b, const float* plw, const float* plb,
    const float* ptraceF, u16* rnn_in, float* d_out)
{
    __shared__ float pre4[64][4];
    __shared__ float pre6[64][6];
    __shared__ float predl[64][2];
    const int tid = threadIdx.x;
    const int pr = t & 1;                    // parity where step t-1 h was written
    if (t > 0) {
        {
            int b = tid >> 2, g = tid & 3;
            const u16* hp = hB + (((size_t)pr * 4 + 3) * 64 + b) * 512;
            float a = lin_b[g];
            const float* wr = lin_w + g * 512;
            for (int k = 0; k < 512; k += 8) {
                short8 v = *(const short8*)(hp + k);
#pragma unroll
                for (int j = 0; j < 8; ++j) a += b2f((u16)v[j]) * wr[k + j];
            }
            pre4[b][g] = a;
        }
        for (int idx = tid; idx < 384; idx += 256) {
            int b = idx / 6, g = idx - b * 6;
            const u16* hp = hP + (((size_t)pr * 4 + 3) * 64 + b) * 512;
            float a = plb[g];
            const float* wr = plw + g * 512;
            for (int k = 0; k < 512; k += 8) {
                short8 v = *(const short8*)(hp + k);
#pragma unroll
                for (int j = 0; j < 8; ++j) a += b2f((u16)v[j]) * wr[k + j];
            }
            pre6[b][g] = a;
        }
    } else {
        if (tid < 128) { int b = tid >> 1, e = tid & 1; predl[b][e] = 0.0f; }
    }
    __syncthreads();
    if (t > 0) {
        if (tid < 128) {
            int b = tid >> 1, e = tid & 1;
            float v = pre4[b][e] * sigf(pre4[b][2 + e]);
            predl[b][e] = v;
            d_out[((size_t)b * 200 + (t - 1)) * 46 + 44 + e] = v * (e ? 68.0f : 105.0f);
        }
        if (tid < 192) {
            int b = tid / 3, e = tid - b * 3;
            float v = pre6[b][e] * sigf(pre6[b][3 + e]);
            d_out[(size_t)588800 + ((size_t)b * 200 + (t - 1)) * 3 + e] = v;
        }
    }
    __syncthreads();
    if (t < 200 && tid < 64) {
        int b = tid;
        float px = predl[b][0], py = predl[b][1];
        float d[22];
#pragma unroll
        for (int p = 0; p < 22; ++p) {
            const float* pt = ptraceF + ((size_t)t * 1408 + b * 22 + p) * 2;
            float dx = px - pt[0], dy = py - pt[1];
            d[p] = sqrtf(dx * dx + dy * dy);
        }
        for (int i = 1; i < 22; ++i) {
            float key = d[i];
            int j = i - 1;
            while (j >= 0 && d[j] > key) { d[j + 1] = d[j]; --j; }
            d[j + 1] = key;
        }
        u16* rp = rnn_in + ((size_t)t * 64 + b) * 640;
#pragma unroll
        for (int k = 0; k < 22; ++k) rp[600 + k] = f2b(d[k]);
        rp[622] = f2b(px);
        rp[623] = f2b(py);
    }
}

// ---------------------------------------------------------------- host
extern "C" void kernel_launch(void* const* d_in, const int* in_sizes, int n_in,
                              void* d_out_v, int out_size, void* d_ws, size_t ws_size,
                              hipStream_t stream)
{
    (void)in_sizes; (void)n_in; (void)out_size; (void)ws_size;
    const float* coords = (const float*)d_in[1];
    const float* stf_w1 = (const float*)d_in[3];
    const float* stf_b1 = (const float*)d_in[4];
    const float* stf_w2 = (const float*)d_in[5];
    const float* stf_b2 = (const float*)d_in[6];
    const float* stf_w3 = (const float*)d_in[7];
    const float* stf_b3 = (const float*)d_in[8];
    const float* tWih0 = (const float*)d_in[9];
    const float* tWihL = (const float*)d_in[10];
    const float* tWhh  = (const float*)d_in[11];
    const float* tbih  = (const float*)d_in[12];
    const float* tbhh  = (const float*)d_in[13];
    const float* bWih0 = (const float*)d_in[14];
    const float* bWihL = (const float*)d_in[15];
    const float* bWhh  = (const float*)d_in[16];
    const float* bbih  = (const float*)d_in[17];
    const float* bbhh  = (const float*)d_in[18];
    const float* pWih0 = (const float*)d_in[19];
    const float* pWihL = (const float*)d_in[20];
    const float* pWhh  = (const float*)d_in[21];
    const float* pbih  = (const float*)d_in[22];
    const float* pbhh  = (const float*)d_in[23];
    const float* lin_w = (const float*)d_in[24];
    const float* lin_b = (const float*)d_in[25];
    const float* lsw   = (const float*)d_in[26];
    const float* lsb   = (const float*)d_in[27];
    const float* plw   = (const float*)d_in[28];
    const float* plb   = (const float*)d_in[29];
    float* d_out = (float*)d_out_v;

    char* ws = (char*)d_ws;
    size_t off = 0;
    auto alloc = [&](size_t bytes) -> char* {
        char* p = ws + off;
        off += (bytes + 255) & ~(size_t)255;
        return p;
    };
    u16*   hT = (u16*)alloc((size_t)4 * 1408 * 128 * 2);
    float* cT = (float*)alloc((size_t)4 * 1408 * 128 * 4);
    u16*   hB = (u16*)alloc((size_t)2 * 4 * 64 * 512 * 2);
    float* cB = (float*)alloc((size_t)4 * 64 * 512 * 4);
    u16*   hP = (u16*)alloc((size_t)2 * 4 * 64 * 512 * 2);
    float* cP = (float*)alloc((size_t)4 * 64 * 512 * 4);
    size_t stateBytes = off;
    u16*   rnn = (u16*)alloc((size_t)200 * 64 * 640 * 2);
    float* ptraceF = (float*)alloc((size_t)200 * 1408 * 2 * 4);
    u16*   packB = (u16*)alloc((size_t)(1152 + 3 * 1024) * 2048 * 2);
    u16*   packP = (u16*)alloc((size_t)(1152 + 3 * 1024) * 2048 * 2);
    u16*   packT = (u16*)alloc((size_t)(128 + 3 * 256) * 512 * 2);
    float* bcB = (float*)alloc((size_t)4 * 2048 * 4);
    float* bcP = (float*)alloc((size_t)4 * 2048 * 4);
    float* bcT = (float*)alloc((size_t)4 * 512 * 4);

    hipMemsetAsync(d_ws, 0, stateBytes, stream);

    auto packLaunch = [&](const float* Wih, int Kih, int Kihp, const float* Whh, int Khh,
                          int N, u16* dst) {
        long total = (long)(N / 16) * ((Kihp + Khh) / 32) * 64;
        int blocks = (int)((total + 255) / 256);
        k_pack<<<dim3(blocks), dim3(256), 0, stream>>>(Wih, Kih, Kihp, Whh, Khh, N, dst);
    };
    packLaunch(bWih0, 624, 640, bWhh, 512, 2048, packB);
    for (int l = 1; l < 4; ++l)
        packLaunch(bWihL + (size_t)(l - 1) * 2048 * 512, 512, 512,
                   bWhh + (size_t)l * 2048 * 512, 512, 2048,
                   packB + (size_t)1152 * 2048 + (size_t)(l - 1) * 1024 * 2048);
    packLaunch(pWih0, 624, 640, pWhh, 512, 2048, packP);
    for (int l = 1; l < 4; ++l)
        packLaunch(pWihL + (size_t)(l - 1) * 2048 * 512, 512, 512,
                   pWhh + (size_t)l * 2048 * 512, 512, 2048,
                   packP + (size_t)1152 * 2048 + (size_t)(l - 1) * 1024 * 2048);
    packLaunch(nullptr, 0, 0, tWhh, 128, 512, packT);
    for (int l = 1; l < 4; ++l)
        packLaunch(tWihL + (size_t)(l - 1) * 512 * 128, 128, 128,
                   tWhh + (size_t)l * 512 * 128, 128, 512,
                   packT + (size_t)128 * 512 + (size_t)(l - 1) * 256 * 512);

    k_bias<<<dim3((18432 + 255) / 256), dim3(256), 0, stream>>>(
        bbih, bbhh, pbih, pbhh, tbih, tbhh, bcB, bcP, bcT);
    k_coords<<<dim3((200 * 64 * 38 + 255) / 256), dim3(256), 0, stream>>>(coords, ptraceF, rnn);
    k_enc<<<dim3(1600), dim3(256), 0, stream>>>(
        ptraceF, stf_w1, stf_b1, stf_w2, stf_b2, stf_w3, stf_b3, rnn);
    k_traj0<<<dim3(88), dim3(256), 0, stream>>>(
        packT, bcT, tWih0, ptraceF, hT, cT, rnn, d_out, lsw, lsb);

    for (int t = 0; t < 200; ++t) {
        k_glue<<<dim3(1), dim3(256), 0, stream>>>(t, hB, hP, lin_w, lin_b, plw, plb,
                                                  ptraceF, rnn, d_out);
        for (int l = 0; l < 4; ++l)
            k_step<<<dim3(152), dim3(256), 0, stream>>>(l, t, rnn, rnn,
                packB, packP, packT, bcB, bcP, bcT,
                hB, cB, hP, cP, hT, cT, tWih0, ptraceF, d_out, lsw, lsb);
    }
    k_glue<<<dim3(1), dim3(256), 0, stream>>>(200, hB, hP, lin_w, lin_b, plw, plb,
                                              ptraceF, rnn, d_out);
}

// Round 2
// 46174.969 us; speedup vs baseline: 1.0421x; 1.0421x over previous
//
#include <hip/hip_runtime.h>
#include <hip/hip_bf16.h>

typedef unsigned short u16;
typedef __attribute__((ext_vector_type(8))) short short8;
typedef __attribute__((ext_vector_type(4))) float f32x4;

__device__ __forceinline__ float sigf(float x) { return 1.0f / (1.0f + __expf(-x)); }
__device__ __forceinline__ float tanhfast(float x) { return 2.0f / (1.0f + __expf(-2.0f * x)) - 1.0f; }
__device__ __forceinline__ u16 f2b(float f) {
    union { float f; unsigned u; } v; v.f = f;
    unsigned u = v.u;
    unsigned r = (u + 0x7FFFu + ((u >> 16) & 1u)) >> 16;
    return (u16)r;
}
__device__ __forceinline__ float b2f(u16 h) {
    union { unsigned u; float f; } v; v.u = ((unsigned)h) << 16;
    return v.f;
}

// ---------------------------------------------------------------- pack kernels
// remap=1 (ball/pos layer0): padded-640 input layout with feedback tail moved to
// cols 608..631 (tile 19), zeros at 600..607 and 632..639.
__global__ void k_pack(const float* Wih, int K_ih, int K_ih_pad, const float* Whh, int K_hh,
                       int N, int remap, u16* dst)
{
    int K = K_ih_pad + K_hh;
    int KT = K >> 5;
    long total = (long)(N >> 4) * KT * 64;
    long idx = (long)blockIdx.x * 256 + threadIdx.x;
    if (idx >= total) return;
    int lane = (int)(idx & 63);
    long t2 = idx >> 6;
    int kt = (int)(t2 % KT);
    long nt = t2 / KT;
    int n = (int)nt * 16 + (lane & 15);
    int kb = kt * 32 + ((lane >> 4) << 3);
    u16* dp = dst + idx * 8;
#pragma unroll
    for (int j = 0; j < 8; ++j) {
        int k = kb + j;
        float v;
        if (k < K_ih_pad) {
            int ks;
            if (remap) {
                if (k < 600) ks = k;
                else if (k < 608) ks = -1;
                else if (k < 632) ks = k - 8;
                else ks = -1;
            } else {
                ks = (k < K_ih) ? k : -1;
            }
            v = (ks >= 0) ? Wih[(size_t)n * K_ih + ks] : 0.0f;
        } else {
            v = Whh[(size_t)n * K_hh + (k - K_ih_pad)];
        }
        dp[j] = f2b(v);
    }
}

__global__ void k_bias(const float* a1, const float* a2, const float* b1, const float* b2,
                       const float* c1, const float* c2, float* oB, float* oP, float* oT)
{
    int idx = blockIdx.x * 256 + threadIdx.x;
    if (idx < 8192) oB[idx] = a1[idx] + a2[idx];
    else if (idx < 16384) { int i = idx - 8192; oP[i] = b1[i] + b2[i]; }
    else if (idx < 18432) { int i = idx - 16384; oT[i] = c1[i] + c2[i]; }
}

// normalize coords -> ptraceF [t][1408][2] f32, rnn_in[t][b][0:44) bf16, zero cols 600..615
__global__ void k_coords(const float* coords, float* ptraceF, u16* rnn_in)
{
    int idx = blockIdx.x * 256 + threadIdx.x;
    if (idx >= 200 * 64 * 38) return;
    int t = idx / (64 * 38);
    int rem = idx - t * (64 * 38);
    int b = rem / 38, s2 = rem - b * 38;
    if (s2 < 22) {
        int p = s2;
        float x = coords[((size_t)b * 200 + t) * 88 + 4 * p] * (1.0f / 105.0f);
        float y = coords[((size_t)b * 200 + t) * 88 + 4 * p + 1] * (1.0f / 68.0f);
        size_t r = (size_t)t * 1408 + b * 22 + p;
        ptraceF[r * 2] = x;
        ptraceF[r * 2 + 1] = y;
        u16* rp = rnn_in + ((size_t)t * 64 + b) * 640;
        rp[2 * p] = f2b(x);
        rp[2 * p + 1] = f2b(y);
    } else {
        int i = s2 - 22;
        rnn_in[((size_t)t * 64 + b) * 640 + 600 + i] = 0;
    }
}

// ---------------------------------------------------------------- set encoder
__global__ __launch_bounds__(256) void k_enc(const float* ptraceF,
    const float* w1, const float* b1, const float* w2, const float* b2,
    const float* w3, const float* b3, u16* rnn_in)
{
    __shared__ u16 w2s[128 * 128];
    __shared__ float w1s[256];
    __shared__ float b1s[128], b2s[128];
    __shared__ float h1s[2][11][128];
    __shared__ float ms[2][128];
    __shared__ float pts[2][11][2];
    const int tid = threadIdx.x;
    for (int i = tid; i < 16384; i += 256) w2s[i] = f2b(w2[i]);
    if (tid < 256) w1s[tid] = w1[tid];
    if (tid < 128) { b1s[tid] = b1[tid]; b2s[tid] = b2[tid]; }
    __syncthreads();
    const int set = tid >> 7, j = tid & 127;
    for (int it = 0; it < 8; ++it) {
        int tb = blockIdx.x * 8 + it;
        int t = tb / 64, b = tb - t * 64;
        if (tid < 44) {
            int pp = tid >> 1, e = tid & 1;
            pts[pp / 11][pp % 11][e] = ptraceF[((size_t)t * 1408 + b * 22 + pp) * 2 + e];
        }
        __syncthreads();
        float h1r[11];
#pragma unroll
        for (int p = 0; p < 11; ++p)
            h1r[p] = fmaxf(0.0f, pts[set][p][0] * w1s[j] + pts[set][p][1] * w1s[128 + j] + b1s[j]);
#pragma unroll
        for (int p = 0; p < 11; ++p) h1s[set][p][j] = h1r[p];
        __syncthreads();
        float ac[11];
#pragma unroll
        for (int p = 0; p < 11; ++p) ac[p] = b2s[j];
        for (int k4 = 0; k4 < 128; k4 += 4) {
            float wv0 = b2f(w2s[(k4 + 0) * 128 + j]);
            float wv1 = b2f(w2s[(k4 + 1) * 128 + j]);
            float wv2 = b2f(w2s[(k4 + 2) * 128 + j]);
            float wv3 = b2f(w2s[(k4 + 3) * 128 + j]);
#pragma unroll
            for (int p = 0; p < 11; ++p) {
                const float4 h4 = *(const float4*)&h1s[set][p][k4];
                ac[p] += h4.x * wv0 + h4.y * wv1 + h4.z * wv2 + h4.w * wv3;
            }
        }
        float msum = 0.0f;
#pragma unroll
        for (int p = 0; p < 11; ++p) msum += fmaxf(0.0f, ac[p]);
        ms[set][j] = msum * (1.0f / 11.0f);
        __syncthreads();
        for (int jo = j; jo < 256; jo += 128) {
            float a = b3[jo];
            for (int k4 = 0; k4 < 128; k4 += 4) {
                const float4 m4 = *(const float4*)&ms[set][k4];
                a += m4.x * w3[(k4 + 0) * 256 + jo] + m4.y * w3[(k4 + 1) * 256 + jo]
                   + m4.z * w3[(k4 + 2) * 256 + jo] + m4.w * w3[(k4 + 3) * 256 + jo];
            }
            rnn_in[((size_t)t * 64 + b) * 640 + 44 + set * 256 + jo] = f2b(a);
        }
        __syncthreads();
    }
}

// ---------------------------------------------------------------- traj layer
struct TrajHalf {
    float xy[16][2];
    float h3[16][128];
    float pre[16][4];
};

__device__ void traj_layer(int l, int s, int r0, int tid,
    const u16* packT, const float* bcT, const float* wih0,
    const float* ptraceF, u16* hT, float* cT,
    u16* rnn_in, float* d_out, const float* lsw, const float* lsb,
    TrajHalf* sm)
{
    const int w = tid >> 6, lane = tid & 63;
    const int quad = lane >> 4, col = lane & 15;
    const int KT = (l == 0) ? 4 : 8;
    const u16* pk = packT + ((l == 0) ? (size_t)0 : ((size_t)128 * 512 + (size_t)(l - 1) * 256 * 512));

    if (l == 0) {
        if (tid < 32) {
            int m = tid >> 1, e = tid & 1;
            sm->xy[m][e] = ptraceF[((size_t)s * 1408 + r0 + m) * 2 + e];
        }
    }
    __syncthreads();

    f32x4 acc[8];
#pragma unroll
    for (int i = 0; i < 8; ++i) {
        int n = (w + 4 * i) * 16 + col;
        float bb = bcT[l * 512 + n];
        if (l == 0) {
            float wx = wih0[n * 2], wy = wih0[n * 2 + 1];
#pragma unroll
            for (int r = 0; r < 4; ++r)
                acc[i][r] = bb + wx * sm->xy[quad * 4 + r][0] + wy * sm->xy[quad * 4 + r][1];
        } else {
#pragma unroll
            for (int r = 0; r < 4; ++r) acc[i][r] = bb;
        }
    }

    for (int kt = 0; kt < KT; ++kt) {
        const u16* ap;
        if (l == 0)
            ap = hT + ((size_t)r0 + col) * 128 + kt * 32 + quad * 8;
        else if (kt < 4)
            ap = hT + ((size_t)(l - 1) * 1408 + r0 + col) * 128 + kt * 32 + quad * 8;
        else
            ap = hT + ((size_t)l * 1408 + r0 + col) * 128 + (kt - 4) * 32 + quad * 8;
        short8 a8 = *(const short8*)ap;
#pragma unroll
        for (int i = 0; i < 8; ++i) {
            int nt = w + 4 * i;
            short8 b8 = *(const short8*)(pk + ((size_t)(nt * KT + kt) * 64 + lane) * 8);
            acc[i] = __builtin_amdgcn_mfma_f32_16x16x32_bf16(a8, b8, acc[i], 0, 0, 0);
        }
    }
    __syncthreads();

#pragma unroll
    for (int h = 0; h < 2; ++h) {
        int j = 64 * h + 16 * w + col;
#pragma unroll
        for (int r = 0; r < 4; ++r) {
            int m = quad * 4 + r;
            size_t ci = ((size_t)l * 1408 + r0 + m) * 128 + j;
            float c_old = cT[ci];
            float cn = sigf(acc[2 + h][r]) * c_old + sigf(acc[0 + h][r]) * tanhfast(acc[4 + h][r]);
            float hn = sigf(acc[6 + h][r]) * tanhfast(cn);
            cT[ci] = cn;
            hT[ci] = f2b(hn);
            if (l == 3) sm->h3[m][j] = hn;
        }
    }

    if (l == 3) {
        __syncthreads();
        if (tid < 64) {
            int m = tid >> 2, g = tid & 3;
            float a = lsb[g];
            const float* wr = lsw + g * 128;
#pragma unroll 8
            for (int k = 0; k < 128; ++k) a += sm->h3[m][k] * wr[k];
            sm->pre[m][g] = a;
        }
        __syncthreads();
        if (tid < 32) {
            int m = tid >> 1, e = tid & 1;
            float v = sm->pre[m][e] * sigf(sm->pre[m][2 + e]);
            int rr = r0 + m, b = rr / 22, p = rr - b * 22;
            rnn_in[((size_t)s * 64 + b) * 640 + 556 + 2 * p + e] = f2b(v);
            d_out[((size_t)b * 200 + s) * 46 + 2 * p + e] = v * (e ? 68.0f : 105.0f);
        }
        __syncthreads();
    } else {
        __syncthreads();
    }
}

// ---------------------------------------------------------------- persistent kernel
struct BallSmem {
    float g[4][64][33];
    u16 tail[64][32];
    float pp[64][8][6];
};
struct TrajSmem2 { TrajHalf h[2]; };
union alignas(16) PersistSmem { BallSmem b; TrajSmem2 t; };

__device__ __forceinline__ void gbar(unsigned* cnt, unsigned* epoch)
{
    __syncthreads();
    if (threadIdx.x == 0) {
        __threadfence();
        __hip_atomic_fetch_add(cnt, 1u, __ATOMIC_RELEASE, __HIP_MEMORY_SCOPE_AGENT);
        unsigned tgt = 32u * (++(*epoch));
        while (__hip_atomic_load(cnt, __ATOMIC_ACQUIRE, __HIP_MEMORY_SCOPE_AGENT) < tgt)
            __builtin_amdgcn_s_sleep(2);
        __threadfence();
    }
    __syncthreads();
}

__global__ __launch_bounds__(512, 1) void k_persist(
    u16* rnn, const u16* packB, const u16* packP, const u16* packT,
    const float* bcB, const float* bcP, const float* bcT,
    u16* hB, float* cB, u16* hP, float* cP, u16* hT, float* cT,
    const float* tWih0, const float* ptraceF,
    float* d_out, const float* lin_w, const float* lin_b,
    const float* lsw, const float* lsb, const float* plw, const float* plb,
    float* pre4g, float* pre6g, unsigned* barCnt, unsigned* trajCnt)
{
    __shared__ PersistSmem sm;
    const int bid = blockIdx.x;
    const int tid = threadIdx.x;

    if (bid >= 32) {
        // ---------------- traj: free-running, no grid barriers
        const int half = tid >> 8;
        const int tid2 = tid & 255;
        const int r0 = (bid - 32) * 32 + half * 16;
        TrajHalf* T = &sm.t.h[half];
        for (int s = 0; s < 200; ++s) {
            for (int l = 0; l < 4; ++l)
                traj_layer(l, s, r0, tid2, packT, bcT, tWih0, ptraceF, hT, cT,
                           rnn, d_out, lsw, lsb, T);
            if (tid == 0) {
                __threadfence();
                __hip_atomic_fetch_add(trajCnt, 1u, __ATOMIC_RELEASE, __HIP_MEMORY_SCOPE_AGENT);
            }
        }
        return;
    }

    // ---------------- ball (bid 0..15) / pos (bid 16..31)
    const int isPos = bid >> 4;
    const int B = bid & 15;
    const u16* pack = isPos ? packP : packB;
    const float* bc = isPos ? bcP : bcB;
    u16* hbuf = isPos ? hP : hB;     // [2][4][64][512] bf16
    float* cbuf = isPos ? cP : cB;   // [4][64][512] f32
    const int ww = tid >> 6, lane = tid & 63;
    const int quad = lane >> 4, col = lane & 15;
    const int part = ww >> 1, sub = ww & 1;
    const int ntile = part * 32 + 2 * B + sub;
    unsigned epoch = 0;

    for (int t = 0; t < 200; ++t) {
        const int pr = t & 1, pw = 1 - pr;
        if (tid == 0) {
            unsigned need = 44u * (unsigned)(t + 1);
            while (__hip_atomic_load(trajCnt, __ATOMIC_RELAXED, __HIP_MEMORY_SCOPE_AGENT) < need)
                __builtin_amdgcn_s_sleep(2);
            __threadfence();
        }
        __syncthreads();

        // glue: feedback tail (dists, step_out) into LDS, redundantly per block
        if (tid < 64) {
            const int b = tid;
            float px = 0.0f, py = 0.0f;
            if (t > 0) {
                const float* p4 = pre4g + ((size_t)(t - 1) * 64 + b) * 4;
                px = (p4[0] + lin_b[0]) * sigf(p4[2] + lin_b[2]);
                py = (p4[1] + lin_b[1]) * sigf(p4[3] + lin_b[3]);
            }
            float d[22];
#pragma unroll
            for (int p = 0; p < 22; ++p) {
                const float* pt = ptraceF + ((size_t)t * 1408 + b * 22 + p) * 2;
                float dx = px - pt[0], dy = py - pt[1];
                d[p] = sqrtf(dx * dx + dy * dy);
            }
            for (int i = 1; i < 22; ++i) {
                float key = d[i];
                int j = i - 1;
                while (j >= 0 && d[j] > key) { d[j + 1] = d[j]; --j; }
                d[j + 1] = key;
            }
#pragma unroll
            for (int k = 0; k < 22; ++k) sm.b.tail[b][k] = f2b(d[k]);
            sm.b.tail[b][22] = f2b(px);
            sm.b.tail[b][23] = f2b(py);
#pragma unroll
            for (int k = 24; k < 32; ++k) sm.b.tail[b][k] = 0;
        }
        if (t > 0) {
            if (bid == 0 && tid >= 64 && tid < 192) {
                int z = tid - 64, b = z >> 1, e = z & 1;
                const float* p4 = pre4g + ((size_t)(t - 1) * 64 + b) * 4;
                float v = (p4[e] + lin_b[e]) * sigf(p4[2 + e] + lin_b[2 + e]);
                d_out[((size_t)b * 200 + (t - 1)) * 46 + 44 + e] = v * (e ? 68.0f : 105.0f);
            }
            if (bid == 16 && tid >= 64 && tid < 256) {
                int z = tid - 64, b = z / 3, g = z - b * 3;
                const float* p6 = pre6g + ((size_t)(t - 1) * 64 + b) * 6;
                float v = (p6[g] + plb[g]) * sigf(p6[3 + g] + plb[3 + g]);
                d_out[(size_t)588800 + ((size_t)b * 200 + (t - 1)) * 3 + g] = v;
            }
        }
        __syncthreads();

        for (int l = 0; l < 4; ++l) {
            const int KT = l ? 32 : 36;
            const u16* pk = pack
                + (l ? ((size_t)128 * 36 * 512 + (size_t)(l - 1) * 128 * 32 * 512) : (size_t)0)
                + ((size_t)ntile * KT) * 512 + (size_t)lane * 8;
            const float bias = bc[l * 2048 + ntile * 16 + col];
            f32x4 acc[4];
#pragma unroll
            for (int m = 0; m < 4; ++m) { acc[m][0] = bias; acc[m][1] = bias; acc[m][2] = bias; acc[m][3] = bias; }

            if (l == 0) {
                for (int kt = 0; kt < 19; ++kt) {
                    short8 b8 = *(const short8*)(pk + (size_t)kt * 512);
#pragma unroll
                    for (int m = 0; m < 4; ++m) {
                        const int row = m * 16 + col;
                        short8 a8 = *(const short8*)(rnn + ((size_t)t * 64 + row) * 640 + kt * 32 + quad * 8);
                        acc[m] = __builtin_amdgcn_mfma_f32_16x16x32_bf16(a8, b8, acc[m], 0, 0, 0);
                    }
                }
                {
                    short8 b8 = *(const short8*)(pk + (size_t)19 * 512);
#pragma unroll
                    for (int m = 0; m < 4; ++m) {
                        const int row = m * 16 + col;
                        short8 a8 = *(const short8*)(&sm.b.tail[row][quad * 8]);
                        acc[m] = __builtin_amdgcn_mfma_f32_16x16x32_bf16(a8, b8, acc[m], 0, 0, 0);
                    }
                }
                for (int kt = 20; kt < 36; ++kt) {
                    short8 b8 = *(const short8*)(pk + (size_t)kt * 512);
#pragma unroll
                    for (int m = 0; m < 4; ++m) {
                        const int row = m * 16 + col;
                        short8 a8 = *(const short8*)(hbuf + (((size_t)pr * 4 + 0) * 64 + row) * 512 + (kt - 20) * 32 + quad * 8);
                        acc[m] = __builtin_amdgcn_mfma_f32_16x16x32_bf16(a8, b8, acc[m], 0, 0, 0);
                    }
                }
            } else {
                for (int kt = 0; kt < 16; ++kt) {
                    short8 b8 = *(const short8*)(pk + (size_t)kt * 512);
#pragma unroll
                    for (int m = 0; m < 4; ++m) {
                        const int row = m * 16 + col;
                        short8 a8 = *(const short8*)(hbuf + (((size_t)pw * 4 + (l - 1)) * 64 + row) * 512 + kt * 32 + quad * 8);
                        acc[m] = __builtin_amdgcn_mfma_f32_16x16x32_bf16(a8, b8, acc[m], 0, 0, 0);
                    }
                }
                for (int kt = 16; kt < 32; ++kt) {
                    short8 b8 = *(const short8*)(pk + (size_t)kt * 512);
#pragma unroll
                    for (int m = 0; m < 4; ++m) {
                        const int row = m * 16 + col;
                        short8 a8 = *(const short8*)(hbuf + (((size_t)pr * 4 + l) * 64 + row) * 512 + (kt - 16) * 32 + quad * 8);
                        acc[m] = __builtin_amdgcn_mfma_f32_16x16x32_bf16(a8, b8, acc[m], 0, 0, 0);
                    }
                }
            }

#pragma unroll
            for (int m = 0; m < 4; ++m)
#pragma unroll
                for (int r = 0; r < 4; ++r)
                    sm.b.g[part][m * 16 + quad * 4 + r][sub * 16 + col] = acc[m][r];
            __syncthreads();
            {
                const int r = tid & 63, t8 = tid >> 6;
                float hnq[4];
#pragma unroll
                for (int q = 0; q < 4; ++q) {
                    const int jl = t8 * 4 + q;
                    float gi = sm.b.g[0][r][jl], gf = sm.b.g[1][r][jl];
                    float gg = sm.b.g[2][r][jl], go = sm.b.g[3][r][jl];
                    size_t ci = ((size_t)l * 64 + r) * 512 + 32 * B + jl;
                    float c_old = cbuf[ci];
                    float cn = sigf(gf) * c_old + sigf(gi) * tanhfast(gg);
                    float hn = sigf(go) * tanhfast(cn);
                    cbuf[ci] = cn;
                    hbuf[(((size_t)pw * 4 + l) * 64 + r) * 512 + 32 * B + jl] = f2b(hn);
                    hnq[q] = hn;
                }
                if (l == 3) {
                    const float* WL = isPos ? plw : lin_w;
                    const int NG = isPos ? 6 : 4;
#pragma unroll
                    for (int g = 0; g < 6; ++g) {
                        float s = 0.0f;
                        if (g < NG) {
#pragma unroll
                            for (int q = 0; q < 4; ++q)
                                s += hnq[q] * WL[g * 512 + 32 * B + t8 * 4 + q];
                        }
                        sm.b.pp[r][t8][g] = s;
                    }
                }
            }
            if (l == 3) {
                __syncthreads();
                if (!isPos) {
                    if (tid < 256) {
                        int r = tid >> 2, g = tid & 3;
                        float s = 0.0f;
#pragma unroll
                        for (int t8 = 0; t8 < 8; ++t8) s += sm.b.pp[r][t8][g];
                        atomicAdd(&pre4g[((size_t)t * 64 + r) * 4 + g], s);
                    }
                } else {
                    if (tid < 384) {
                        int r = tid / 6, g = tid - r * 6;
                        float s = 0.0f;
#pragma unroll
                        for (int t8 = 0; t8 < 8; ++t8) s += sm.b.pp[r][t8][g];
                        atomicAdd(&pre6g[((size_t)t * 64 + r) * 6 + g], s);
                    }
                }
            }
            gbar(barCnt, &epoch);
        }
    }

    // final outputs for t = 199
    if (bid == 0 && tid < 128) {
        int b = tid >> 1, e = tid & 1;
        const float* p4 = pre4g + ((size_t)199 * 64 + b) * 4;
        float v = (p4[e] + lin_b[e]) * sigf(p4[2 + e] + lin_b[2 + e]);
        d_out[((size_t)b * 200 + 199) * 46 + 44 + e] = v * (e ? 68.0f : 105.0f);
    }
    if (bid == 16 && tid < 192) {
        int b = tid / 3, g = tid - b * 3;
        const float* p6 = pre6g + ((size_t)199 * 64 + b) * 6;
        float v = (p6[g] + plb[g]) * sigf(p6[3 + g] + plb[3 + g]);
        d_out[(size_t)588800 + ((size_t)b * 200 + 199) * 3 + g] = v;
    }
}

// ---------------------------------------------------------------- host
extern "C" void kernel_launch(void* const* d_in, const int* in_sizes, int n_in,
                              void* d_out_v, int out_size, void* d_ws, size_t ws_size,
                              hipStream_t stream)
{
    (void)in_sizes; (void)n_in; (void)out_size; (void)ws_size;
    const float* coords = (const float*)d_in[1];
    const float* stf_w1 = (const float*)d_in[3];
    const float* stf_b1 = (const float*)d_in[4];
    const float* stf_w2 = (const float*)d_in[5];
    const float* stf_b2 = (const float*)d_in[6];
    const float* stf_w3 = (const float*)d_in[7];
    const float* stf_b3 = (const float*)d_in[8];
    const float* tWih0 = (const float*)d_in[9];
    const float* tWihL = (const float*)d_in[10];
    const float* tWhh  = (const float*)d_in[11];
    const float* tbih  = (const float*)d_in[12];
    const float* tbhh  = (const float*)d_in[13];
    const float* bWih0 = (const float*)d_in[14];
    const float* bWihL = (const float*)d_in[15];
    const float* bWhh  = (const float*)d_in[16];
    const float* bbih  = (const float*)d_in[17];
    const float* bbhh  = (const float*)d_in[18];
    const float* pWih0 = (const float*)d_in[19];
    const float* pWihL = (const float*)d_in[20];
    const float* pWhh  = (const float*)d_in[21];
    const float* pbih  = (const float*)d_in[22];
    const float* pbhh  = (const float*)d_in[23];
    const float* lin_w = (const float*)d_in[24];
    const float* lin_b = (const float*)d_in[25];
    const float* lsw   = (const float*)d_in[26];
    const float* lsb   = (const float*)d_in[27];
    const float* plw   = (const float*)d_in[28];
    const float* plb   = (const float*)d_in[29];
    float* d_out = (float*)d_out_v;

    char* ws = (char*)d_ws;
    size_t off = 0;
    auto alloc = [&](size_t bytes) -> char* {
        char* p = ws + off;
        off += (bytes + 255) & ~(size_t)255;
        return p;
    };
    // ---- zeroed state zone
    u16*   hT = (u16*)alloc((size_t)4 * 1408 * 128 * 2);
    float* cT = (float*)alloc((size_t)4 * 1408 * 128 * 4);
    u16*   hB = (u16*)alloc((size_t)2 * 4 * 64 * 512 * 2);
    float* cB = (float*)alloc((size_t)4 * 64 * 512 * 4);
    u16*   hP = (u16*)alloc((size_t)2 * 4 * 64 * 512 * 2);
    float* cP = (float*)alloc((size_t)4 * 64 * 512 * 4);
    float* pre4g = (float*)alloc((size_t)200 * 64 * 4 * 4);
    float* pre6g = (float*)alloc((size_t)200 * 64 * 6 * 4);
    unsigned* cnts = (unsigned*)alloc(256);
    size_t stateBytes = off;
    // ---- recomputed-each-call zone
    u16*   rnn = (u16*)alloc((size_t)200 * 64 * 640 * 2);
    float* ptraceF = (float*)alloc((size_t)200 * 1408 * 2 * 4);
    u16*   packB = (u16*)alloc(((size_t)128 * 36 * 512 + (size_t)3 * 128 * 32 * 512) * 2);
    u16*   packP = (u16*)alloc(((size_t)128 * 36 * 512 + (size_t)3 * 128 * 32 * 512) * 2);
    u16*   packT = (u16*)alloc((size_t)(128 + 3 * 256) * 512 * 2);
    float* bcB = (float*)alloc((size_t)4 * 2048 * 4);
    float* bcP = (float*)alloc((size_t)4 * 2048 * 4);
    float* bcT = (float*)alloc((size_t)4 * 512 * 4);

    unsigned* barCnt = cnts;
    unsigned* trajCnt = cnts + 32;

    hipMemsetAsync(d_ws, 0, stateBytes, stream);

    auto packLaunch = [&](const float* Wih, int Kih, int Kihp, const float* Whh, int Khh,
                          int N, int remap, u16* dst) {
        long total = (long)(N / 16) * ((Kihp + Khh) / 32) * 64;
        int blocks = (int)((total + 255) / 256);
        k_pack<<<dim3(blocks), dim3(256), 0, stream>>>(Wih, Kih, Kihp, Whh, Khh, N, remap, dst);
    };
    packLaunch(bWih0, 624, 640, bWhh, 512, 2048, 1, packB);
    for (int l = 1; l < 4; ++l)
        packLaunch(bWihL + (size_t)(l - 1) * 2048 * 512, 512, 512,
                   bWhh + (size_t)l * 2048 * 512, 512, 2048, 0,
                   packB + (size_t)128 * 36 * 512 + (size_t)(l - 1) * 128 * 32 * 512);
    packLaunch(pWih0, 624, 640, pWhh, 512, 2048, 1, packP);
    for (int l = 1; l < 4; ++l)
        packLaunch(pWihL + (size_t)(l - 1) * 2048 * 512, 512, 512,
                   pWhh + (size_t)l * 2048 * 512, 512, 2048, 0,
                   packP + (size_t)128 * 36 * 512 + (size_t)(l - 1) * 128 * 32 * 512);
    packLaunch(nullptr, 0, 0, tWhh, 128, 512, 0, packT);
    for (int l = 1; l < 4; ++l)
        packLaunch(tWihL + (size_t)(l - 1) * 512 * 128, 128, 128,
                   tWhh + (size_t)l * 512 * 128, 128, 512, 0,
                   packT + (size_t)128 * 512 + (size_t)(l - 1) * 256 * 512);

    k_bias<<<dim3((18432 + 255) / 256), dim3(256), 0, stream>>>(
        bbih, bbhh, pbih, pbhh, tbih, tbhh, bcB, bcP, bcT);
    k_coords<<<dim3((200 * 64 * 38 + 255) / 256), dim3(256), 0, stream>>>(coords, ptraceF, rnn);
    k_enc<<<dim3(1600), dim3(256), 0, stream>>>(
        ptraceF, stf_w1, stf_b1, stf_w2, stf_b2, stf_w3, stf_b3, rnn);

    k_persist<<<dim3(76), dim3(512), 0, stream>>>(
        rnn, packB, packP, packT, bcB, bcP, bcT,
        hB, cB, hP, cP, hT, cT, tWih0, ptraceF,
        d_out, lin_w, lin_b, lsw, lsb, plw, plb,
        pre4g, pre6g, barCnt, trajCnt);
}

// Round 3
// 36712.726 us; speedup vs baseline: 1.3107x; 1.2577x over previous
//
#include <hip/hip_runtime.h>
#include <hip/hip_bf16.h>

typedef unsigned short u16;
typedef __attribute__((ext_vector_type(8))) short short8;
typedef __attribute__((ext_vector_type(4))) float f32x4;

__device__ __forceinline__ float sigf(float x) { return 1.0f / (1.0f + __expf(-x)); }
__device__ __forceinline__ float tanhfast(float x) { return 2.0f / (1.0f + __expf(-2.0f * x)) - 1.0f; }
__device__ __forceinline__ u16 f2b(float f) {
    union { float f; unsigned u; } v; v.f = f;
    unsigned u = v.u;
    unsigned r = (u + 0x7FFFu + ((u >> 16) & 1u)) >> 16;
    return (u16)r;
}
__device__ __forceinline__ float b2f(u16 h) {
    union { unsigned u; float f; } v; v.u = ((unsigned)h) << 16;
    return v.f;
}
// write-through stores: bypass L2, land in LLC (cross-XCD visible, no fences)
__device__ __forceinline__ void store_sc1_b64(u16* p, unsigned lo, unsigned hi) {
    uint2 v; v.x = lo; v.y = hi;
    asm volatile("global_store_dwordx2 %0, %1, off sc0 sc1" :: "v"(p), "v"(v) : "memory");
}
__device__ __forceinline__ void store_sc1_b32(u16* p, unsigned v) {
    asm volatile("global_store_dword %0, %1, off sc0 sc1" :: "v"(p), "v"(v) : "memory");
}

// ---------------------------------------------------------------- pack kernels
__global__ void k_pack(const float* Wih, int K_ih, int K_ih_pad, const float* Whh, int K_hh,
                       int N, int remap, u16* dst)
{
    int K = K_ih_pad + K_hh;
    int KT = K >> 5;
    long total = (long)(N >> 4) * KT * 64;
    long idx = (long)blockIdx.x * 256 + threadIdx.x;
    if (idx >= total) return;
    int lane = (int)(idx & 63);
    long t2 = idx >> 6;
    int kt = (int)(t2 % KT);
    long nt = t2 / KT;
    int n = (int)nt * 16 + (lane & 15);
    int kb = kt * 32 + ((lane >> 4) << 3);
    u16* dp = dst + idx * 8;
#pragma unroll
    for (int j = 0; j < 8; ++j) {
        int k = kb + j;
        float v;
        if (k < K_ih_pad) {
            int ks;
            if (remap) {
                if (k < 600) ks = k;
                else if (k < 608) ks = -1;
                else if (k < 632) ks = k - 8;
                else ks = -1;
            } else {
                ks = (k < K_ih) ? k : -1;
            }
            v = (ks >= 0) ? Wih[(size_t)n * K_ih + ks] : 0.0f;
        } else {
            v = Whh[(size_t)n * K_hh + (k - K_ih_pad)];
        }
        dp[j] = f2b(v);
    }
}

__global__ void k_bias(const float* a1, const float* a2, const float* b1, const float* b2,
                       const float* c1, const float* c2, float* oB, float* oP, float* oT)
{
    int idx = blockIdx.x * 256 + threadIdx.x;
    if (idx < 8192) oB[idx] = a1[idx] + a2[idx];
    else if (idx < 16384) { int i = idx - 8192; oP[i] = b1[i] + b2[i]; }
    else if (idx < 18432) { int i = idx - 16384; oT[i] = c1[i] + c2[i]; }
}

// normalize coords -> ptraceF [t][1408][2] f32, rnn_in[t][b][0:44) bf16, zero cols 600..615
__global__ void k_coords(const float* coords, float* ptraceF, u16* rnn_in)
{
    int idx = blockIdx.x * 256 + threadIdx.x;
    if (idx >= 200 * 64 * 38) return;
    int t = idx / (64 * 38);
    int rem = idx - t * (64 * 38);
    int b = rem / 38, s2 = rem - b * 38;
    if (s2 < 22) {
        int p = s2;
        float x = coords[((size_t)b * 200 + t) * 88 + 4 * p] * (1.0f / 105.0f);
        float y = coords[((size_t)b * 200 + t) * 88 + 4 * p + 1] * (1.0f / 68.0f);
        size_t r = (size_t)t * 1408 + b * 22 + p;
        ptraceF[r * 2] = x;
        ptraceF[r * 2 + 1] = y;
        u16* rp = rnn_in + ((size_t)t * 64 + b) * 640;
        rp[2 * p] = f2b(x);
        rp[2 * p + 1] = f2b(y);
    } else {
        int i = s2 - 22;
        rnn_in[((size_t)t * 64 + b) * 640 + 600 + i] = 0;
    }
}

// ---------------------------------------------------------------- set encoder
__global__ __launch_bounds__(256) void k_enc(const float* ptraceF,
    const float* w1, const float* b1, const float* w2, const float* b2,
    const float* w3, const float* b3, u16* rnn_in)
{
    __shared__ u16 w2s[128 * 128];
    __shared__ float w1s[256];
    __shared__ float b1s[128], b2s[128];
    __shared__ float h1s[2][11][128];
    __shared__ float ms[2][128];
    __shared__ float pts[2][11][2];
    const int tid = threadIdx.x;
    for (int i = tid; i < 16384; i += 256) w2s[i] = f2b(w2[i]);
    if (tid < 256) w1s[tid] = w1[tid];
    if (tid < 128) { b1s[tid] = b1[tid]; b2s[tid] = b2[tid]; }
    __syncthreads();
    const int set = tid >> 7, j = tid & 127;
    for (int it = 0; it < 8; ++it) {
        int tb = blockIdx.x * 8 + it;
        int t = tb / 64, b = tb - t * 64;
        if (tid < 44) {
            int pp = tid >> 1, e = tid & 1;
            pts[pp / 11][pp % 11][e] = ptraceF[((size_t)t * 1408 + b * 22 + pp) * 2 + e];
        }
        __syncthreads();
        float h1r[11];
#pragma unroll
        for (int p = 0; p < 11; ++p)
            h1r[p] = fmaxf(0.0f, pts[set][p][0] * w1s[j] + pts[set][p][1] * w1s[128 + j] + b1s[j]);
#pragma unroll
        for (int p = 0; p < 11; ++p) h1s[set][p][j] = h1r[p];
        __syncthreads();
        float ac[11];
#pragma unroll
        for (int p = 0; p < 11; ++p) ac[p] = b2s[j];
        for (int k4 = 0; k4 < 128; k4 += 4) {
            float wv0 = b2f(w2s[(k4 + 0) * 128 + j]);
            float wv1 = b2f(w2s[(k4 + 1) * 128 + j]);
            float wv2 = b2f(w2s[(k4 + 2) * 128 + j]);
            float wv3 = b2f(w2s[(k4 + 3) * 128 + j]);
#pragma unroll
            for (int p = 0; p < 11; ++p) {
                const float4 h4 = *(const float4*)&h1s[set][p][k4];
                ac[p] += h4.x * wv0 + h4.y * wv1 + h4.z * wv2 + h4.w * wv3;
            }
        }
        float msum = 0.0f;
#pragma unroll
        for (int p = 0; p < 11; ++p) msum += fmaxf(0.0f, ac[p]);
        ms[set][j] = msum * (1.0f / 11.0f);
        __syncthreads();
        for (int jo = j; jo < 256; jo += 128) {
            float a = b3[jo];
            for (int k4 = 0; k4 < 128; k4 += 4) {
                const float4 m4 = *(const float4*)&ms[set][k4];
                a += m4.x * w3[(k4 + 0) * 256 + jo] + m4.y * w3[(k4 + 1) * 256 + jo]
                   + m4.z * w3[(k4 + 2) * 256 + jo] + m4.w * w3[(k4 + 3) * 256 + jo];
            }
            rnn_in[((size_t)t * 64 + b) * 640 + 44 + set * 256 + jo] = f2b(a);
        }
        __syncthreads();
    }
}

// ---------------------------------------------------------------- traj layer
struct TrajHalf {
    float xy[16][2];
    float h3[16][128];
    float pre[16][4];
};

__device__ void traj_layer(int l, int s, int r0, int tid,
    const u16* packT, const float* bcT, const float* wih0,
    const float* ptraceF, u16* hT, float* cT,
    u16* rnn_in, float* d_out, const float* lsw, const float* lsb,
    TrajHalf* sm)
{
    const int w = tid >> 6, lane = tid & 63;
    const int quad = lane >> 4, col = lane & 15;
    const int KT = (l == 0) ? 4 : 8;
    const u16* pk = packT + ((l == 0) ? (size_t)0 : ((size_t)128 * 512 + (size_t)(l - 1) * 256 * 512));

    if (l == 0) {
        if (tid < 32) {
            int m = tid >> 1, e = tid & 1;
            sm->xy[m][e] = ptraceF[((size_t)s * 1408 + r0 + m) * 2 + e];
        }
    }
    __syncthreads();

    f32x4 acc[8];
#pragma unroll
    for (int i = 0; i < 8; ++i) {
        int n = (w + 4 * i) * 16 + col;
        float bb = bcT[l * 512 + n];
        if (l == 0) {
            float wx = wih0[n * 2], wy = wih0[n * 2 + 1];
#pragma unroll
            for (int r = 0; r < 4; ++r)
                acc[i][r] = bb + wx * sm->xy[quad * 4 + r][0] + wy * sm->xy[quad * 4 + r][1];
        } else {
#pragma unroll
            for (int r = 0; r < 4; ++r) acc[i][r] = bb;
        }
    }

    for (int kt = 0; kt < KT; ++kt) {
        const u16* ap;
        if (l == 0)
            ap = hT + ((size_t)r0 + col) * 128 + kt * 32 + quad * 8;
        else if (kt < 4)
            ap = hT + ((size_t)(l - 1) * 1408 + r0 + col) * 128 + kt * 32 + quad * 8;
        else
            ap = hT + ((size_t)l * 1408 + r0 + col) * 128 + (kt - 4) * 32 + quad * 8;
        short8 a8 = *(const short8*)ap;
#pragma unroll
        for (int i = 0; i < 8; ++i) {
            int nt = w + 4 * i;
            short8 b8 = *(const short8*)(pk + ((size_t)(nt * KT + kt) * 64 + lane) * 8);
            acc[i] = __builtin_amdgcn_mfma_f32_16x16x32_bf16(a8, b8, acc[i], 0, 0, 0);
        }
    }
    __syncthreads();

#pragma unroll
    for (int h = 0; h < 2; ++h) {
        int j = 64 * h + 16 * w + col;
#pragma unroll
        for (int r = 0; r < 4; ++r) {
            int m = quad * 4 + r;
            size_t ci = ((size_t)l * 1408 + r0 + m) * 128 + j;
            float c_old = cT[ci];
            float cn = sigf(acc[2 + h][r]) * c_old + sigf(acc[0 + h][r]) * tanhfast(acc[4 + h][r]);
            float hn = sigf(acc[6 + h][r]) * tanhfast(cn);
            cT[ci] = cn;
            hT[ci] = f2b(hn);
            if (l == 3) sm->h3[m][j] = hn;
        }
    }

    if (l == 3) {
        __syncthreads();
        if (tid < 64) {
            int m = tid >> 2, g = tid & 3;
            float a = lsb[g];
            const float* wr = lsw + g * 128;
#pragma unroll 8
            for (int k = 0; k < 128; ++k) a += sm->h3[m][k] * wr[k];
            sm->pre[m][g] = a;
        }
        __syncthreads();
        if (tid < 16) {
            int m = tid;
            float vx = sm->pre[m][0] * sigf(sm->pre[m][2]);
            float vy = sm->pre[m][1] * sigf(sm->pre[m][3]);
            int rr = r0 + m, b = rr / 22, p = rr - b * 22;
            store_sc1_b32(rnn_in + ((size_t)s * 64 + b) * 640 + 556 + 2 * p,
                          (unsigned)f2b(vx) | ((unsigned)f2b(vy) << 16));
            d_out[((size_t)b * 200 + s) * 46 + 2 * p] = vx * 105.0f;
            d_out[((size_t)b * 200 + s) * 46 + 2 * p + 1] = vy * 68.0f;
        }
        __syncthreads();
    } else {
        __syncthreads();
    }
}

// ---------------------------------------------------------------- persistent kernel
struct BallSmem {
    float g[4][64][33];
    u16 tail[64][32];
    float pp[64][8][6];
};
struct TrajSmem2 { TrajHalf h[2]; };
union alignas(16) PersistSmem { BallSmem b; TrajSmem2 t; };

// fence-free barrier: RELAXED sc1 atomics; producer data already at LLC via
// sc1 stores drained by __syncthreads' vmcnt(0); consumer reads are cold lines.
__device__ __forceinline__ void gbar(unsigned* cnt, unsigned* epoch)
{
    __syncthreads();
    if (threadIdx.x == 0) {
        __hip_atomic_fetch_add(cnt, 1u, __ATOMIC_RELAXED, __HIP_MEMORY_SCOPE_AGENT);
        unsigned tgt = 32u * (++(*epoch));
        while (__hip_atomic_load(cnt, __ATOMIC_RELAXED, __HIP_MEMORY_SCOPE_AGENT) < tgt)
            __builtin_amdgcn_s_sleep(2);
    }
    __syncthreads();
}

__global__ __launch_bounds__(512, 1) void k_persist(
    u16* rnn, const u16* packB, const u16* packP, const u16* packT,
    const float* bcB, const float* bcP, const float* bcT,
    u16* hRB, u16* hRP, const u16* hZ, float* cB, float* cP, u16* hT, float* cT,
    const float* tWih0, const float* ptraceF,
    float* d_out, const float* lin_w, const float* lin_b,
    const float* lsw, const float* lsb, const float* plw, const float* plb,
    float* pre4g, float* pre6g, unsigned* barCnt, unsigned* trajCnt)
{
    __shared__ PersistSmem sm;
    const int bid = blockIdx.x;
    const int tid = threadIdx.x;

    if (bid >= 32) {
        // ---------------- traj: free-running, no grid barriers
        const int half = tid >> 8;
        const int tid2 = tid & 255;
        const int r0 = (bid - 32) * 32 + half * 16;
        TrajHalf* T = &sm.t.h[half];
        for (int s = 0; s < 200; ++s) {
            for (int l = 0; l < 4; ++l)
                traj_layer(l, s, r0, tid2, packT, bcT, tWih0, ptraceF, hT, cT,
                           rnn, d_out, lsw, lsb, T);
            if (tid == 0)
                __hip_atomic_fetch_add(trajCnt, 1u, __ATOMIC_RELAXED, __HIP_MEMORY_SCOPE_AGENT);
        }
        return;
    }

    // ---------------- ball (bid 0..15) / pos (bid 16..31)
    const int isPos = bid >> 4;
    const int B = bid & 15;
    const u16* pack = isPos ? packP : packB;
    const float* bc = isPos ? bcP : bcB;
    u16* ring = isPos ? hRP : hRB;   // [200][4][64][512] bf16, write-once
    float* cbuf = isPos ? cP : cB;   // [4][64][512] f32 (block-private columns)
    const int ww = tid >> 6, lane = tid & 63;
    const int quad = lane >> 4, col = lane & 15;
    const int part = ww >> 1, sub = ww & 1;
    const int ntile = part * 32 + 2 * B + sub;
    unsigned epoch = 0;

    for (int t = 0; t < 200; ++t) {
        if (tid == 0) {
            unsigned need = 44u * (unsigned)(t + 1);
            while (__hip_atomic_load(trajCnt, __ATOMIC_RELAXED, __HIP_MEMORY_SCOPE_AGENT) < need)
                __builtin_amdgcn_s_sleep(2);
        }
        __syncthreads();

        // glue: feedback tail (dists, step_out) into LDS, redundantly per block
        if (tid < 64) {
            const int b = tid;
            float px = 0.0f, py = 0.0f;
            if (t > 0) {
                const float* p4 = pre4g + ((size_t)(t - 1) * 64 + b) * 4;
                px = (p4[0] + lin_b[0]) * sigf(p4[2] + lin_b[2]);
                py = (p4[1] + lin_b[1]) * sigf(p4[3] + lin_b[3]);
            }
            float d[22];
#pragma unroll
            for (int p = 0; p < 22; ++p) {
                const float* pt = ptraceF + ((size_t)t * 1408 + b * 22 + p) * 2;
                float dx = px - pt[0], dy = py - pt[1];
                d[p] = sqrtf(dx * dx + dy * dy);
            }
            for (int i = 1; i < 22; ++i) {
                float key = d[i];
                int j = i - 1;
                while (j >= 0 && d[j] > key) { d[j + 1] = d[j]; --j; }
                d[j + 1] = key;
            }
#pragma unroll
            for (int k = 0; k < 22; ++k) sm.b.tail[b][k] = f2b(d[k]);
            sm.b.tail[b][22] = f2b(px);
            sm.b.tail[b][23] = f2b(py);
#pragma unroll
            for (int k = 24; k < 32; ++k) sm.b.tail[b][k] = 0;
        }
        if (t > 0) {
            if (bid == 0 && tid >= 64 && tid < 192) {
                int z = tid - 64, b = z >> 1, e = z & 1;
                const float* p4 = pre4g + ((size_t)(t - 1) * 64 + b) * 4;
                float v = (p4[e] + lin_b[e]) * sigf(p4[2 + e] + lin_b[2 + e]);
                d_out[((size_t)b * 200 + (t - 1)) * 46 + 44 + e] = v * (e ? 68.0f : 105.0f);
            }
            if (bid == 16 && tid >= 64 && tid < 256) {
                int z = tid - 64, b = z / 3, g = z - b * 3;
                const float* p6 = pre6g + ((size_t)(t - 1) * 64 + b) * 6;
                float v = (p6[g] + plb[g]) * sigf(p6[3 + g] + plb[3 + g]);
                d_out[(size_t)588800 + ((size_t)b * 200 + (t - 1)) * 3 + g] = v;
            }
        }
        __syncthreads();

        for (int l = 0; l < 4; ++l) {
            const int KT = l ? 32 : 36;
            const u16* pk = pack
                + (l ? ((size_t)128 * 36 * 512 + (size_t)(l - 1) * 128 * 32 * 512) : (size_t)0)
                + ((size_t)ntile * KT) * 512 + (size_t)lane * 8;
            const float bias = bc[l * 2048 + ntile * 16 + col];
            const u16* hPrevNew = ring + (((size_t)t * 4 + (l - 1)) * 64) * 512;       // l>=1
            const u16* hSelfOld = (t == 0) ? (hZ + (size_t)l * 64 * 512)
                                           : ring + (((size_t)(t - 1) * 4 + l) * 64) * 512;
            f32x4 acc[4];
#pragma unroll
            for (int m = 0; m < 4; ++m) { acc[m][0] = bias; acc[m][1] = bias; acc[m][2] = bias; acc[m][3] = bias; }

            if (l == 0) {
                for (int kt = 0; kt < 19; ++kt) {
                    short8 b8 = *(const short8*)(pk + (size_t)kt * 512);
#pragma unroll
                    for (int m = 0; m < 4; ++m) {
                        const int row = m * 16 + col;
                        short8 a8 = *(const short8*)(rnn + ((size_t)t * 64 + row) * 640 + kt * 32 + quad * 8);
                        acc[m] = __builtin_amdgcn_mfma_f32_16x16x32_bf16(a8, b8, acc[m], 0, 0, 0);
                    }
                }
                {
                    short8 b8 = *(const short8*)(pk + (size_t)19 * 512);
#pragma unroll
                    for (int m = 0; m < 4; ++m) {
                        const int row = m * 16 + col;
                        short8 a8 = *(const short8*)(&sm.b.tail[row][quad * 8]);
                        acc[m] = __builtin_amdgcn_mfma_f32_16x16x32_bf16(a8, b8, acc[m], 0, 0, 0);
                    }
                }
                for (int kt = 20; kt < 36; ++kt) {
                    short8 b8 = *(const short8*)(pk + (size_t)kt * 512);
#pragma unroll
                    for (int m = 0; m < 4; ++m) {
                        const int row = m * 16 + col;
                        short8 a8 = *(const short8*)(hSelfOld + (size_t)row * 512 + (kt - 20) * 32 + quad * 8);
                        acc[m] = __builtin_amdgcn_mfma_f32_16x16x32_bf16(a8, b8, acc[m], 0, 0, 0);
                    }
                }
            } else {
                for (int kt = 0; kt < 16; ++kt) {
                    short8 b8 = *(const short8*)(pk + (size_t)kt * 512);
#pragma unroll
                    for (int m = 0; m < 4; ++m) {
                        const int row = m * 16 + col;
                        short8 a8 = *(const short8*)(hPrevNew + (size_t)row * 512 + kt * 32 + quad * 8);
                        acc[m] = __builtin_amdgcn_mfma_f32_16x16x32_bf16(a8, b8, acc[m], 0, 0, 0);
                    }
                }
                for (int kt = 16; kt < 32; ++kt) {
                    short8 b8 = *(const short8*)(pk + (size_t)kt * 512);
#pragma unroll
                    for (int m = 0; m < 4; ++m) {
                        const int row = m * 16 + col;
                        short8 a8 = *(const short8*)(hSelfOld + (size_t)row * 512 + (kt - 16) * 32 + quad * 8);
                        acc[m] = __builtin_amdgcn_mfma_f32_16x16x32_bf16(a8, b8, acc[m], 0, 0, 0);
                    }
                }
            }

#pragma unroll
            for (int m = 0; m < 4; ++m)
#pragma unroll
                for (int r = 0; r < 4; ++r)
                    sm.b.g[part][m * 16 + quad * 4 + r][sub * 16 + col] = acc[m][r];
            __syncthreads();
            {
                const int r = tid & 63, t8 = tid >> 6;
                float hnq[4];
#pragma unroll
                for (int q = 0; q < 4; ++q) {
                    const int jl = t8 * 4 + q;
                    float gi = sm.b.g[0][r][jl], gf = sm.b.g[1][r][jl];
                    float gg = sm.b.g[2][r][jl], go = sm.b.g[3][r][jl];
                    size_t ci = ((size_t)l * 64 + r) * 512 + 32 * B + jl;
                    float c_old = cbuf[ci];
                    float cn = sigf(gf) * c_old + sigf(gi) * tanhfast(gg);
                    float hn = sigf(go) * tanhfast(cn);
                    cbuf[ci] = cn;
                    hnq[q] = hn;
                }
                u16* wp = ring + (((size_t)t * 4 + l) * 64 + r) * 512 + 32 * B + t8 * 4;
                store_sc1_b64(wp, (unsigned)f2b(hnq[0]) | ((unsigned)f2b(hnq[1]) << 16),
                                  (unsigned)f2b(hnq[2]) | ((unsigned)f2b(hnq[3]) << 16));
                if (l == 3) {
                    const float* WL = isPos ? plw : lin_w;
                    const int NG = isPos ? 6 : 4;
#pragma unroll
                    for (int g = 0; g < 6; ++g) {
                        float s = 0.0f;
                        if (g < NG) {
#pragma unroll
                            for (int q = 0; q < 4; ++q)
                                s += hnq[q] * WL[g * 512 + 32 * B + t8 * 4 + q];
                        }
                        sm.b.pp[r][t8][g] = s;
                    }
                }
            }
            if (l == 3) {
                __syncthreads();
                if (!isPos) {
                    if (tid < 256) {
                        int r = tid >> 2, g = tid & 3;
                        float s = 0.0f;
#pragma unroll
                        for (int t8 = 0; t8 < 8; ++t8) s += sm.b.pp[r][t8][g];
                        __hip_atomic_fetch_add(&pre4g[((size_t)t * 64 + r) * 4 + g], s,
                                               __ATOMIC_RELAXED, __HIP_MEMORY_SCOPE_AGENT);
                    }
                } else {
                    if (tid < 384) {
                        int r = tid / 6, g = tid - r * 6;
                        float s = 0.0f;
#pragma unroll
                        for (int t8 = 0; t8 < 8; ++t8) s += sm.b.pp[r][t8][g];
                        __hip_atomic_fetch_add(&pre6g[((size_t)t * 64 + r) * 6 + g], s,
                                               __ATOMIC_RELAXED, __HIP_MEMORY_SCOPE_AGENT);
                    }
                }
            }
            gbar(barCnt, &epoch);
        }
    }

    // final outputs for t = 199
    if (bid == 0 && tid < 128) {
        int b = tid >> 1, e = tid & 1;
        const float* p4 = pre4g + ((size_t)199 * 64 + b) * 4;
        float v = (p4[e] + lin_b[e]) * sigf(p4[2 + e] + lin_b[2 + e]);
        d_out[((size_t)b * 200 + 199) * 46 + 44 + e] = v * (e ? 68.0f : 105.0f);
    }
    if (bid == 16 && tid < 192) {
        int b = tid / 3, g = tid - b * 3;
        const float* p6 = pre6g + ((size_t)199 * 64 + b) * 6;
        float v = (p6[g] + plb[g]) * sigf(p6[3 + g] + plb[3 + g]);
        d_out[(size_t)588800 + ((size_t)b * 200 + 199) * 3 + g] = v;
    }
}

// ---------------------------------------------------------------- host
extern "C" void kernel_launch(void* const* d_in, const int* in_sizes, int n_in,
                              void* d_out_v, int out_size, void* d_ws, size_t ws_size,
                              hipStream_t stream)
{
    (void)in_sizes; (void)n_in; (void)out_size; (void)ws_size;
    const float* coords = (const float*)d_in[1];
    const float* stf_w1 = (const float*)d_in[3];
    const float* stf_b1 = (const float*)d_in[4];
    const float* stf_w2 = (const float*)d_in[5];
    const float* stf_b2 = (const float*)d_in[6];
    const float* stf_w3 = (const float*)d_in[7];
    const float* stf_b3 = (const float*)d_in[8];
    const float* tWih0 = (const float*)d_in[9];
    const float* tWihL = (const float*)d_in[10];
    const float* tWhh  = (const float*)d_in[11];
    const float* tbih  = (const float*)d_in[12];
    const float* tbhh  = (const float*)d_in[13];
    const float* bWih0 = (const float*)d_in[14];
    const float* bWihL = (const float*)d_in[15];
    const float* bWhh  = (const float*)d_in[16];
    const float* bbih  = (const float*)d_in[17];
    const float* bbhh  = (const float*)d_in[18];
    const float* pWih0 = (const float*)d_in[19];
    const float* pWihL = (const float*)d_in[20];
    const float* pWhh  = (const float*)d_in[21];
    const float* pbih  = (const float*)d_in[22];
    const float* pbhh  = (const float*)d_in[23];
    const float* lin_w = (const float*)d_in[24];
    const float* lin_b = (const float*)d_in[25];
    const float* lsw   = (const float*)d_in[26];
    const float* lsb   = (const float*)d_in[27];
    const float* plw   = (const float*)d_in[28];
    const float* plb   = (const float*)d_in[29];
    float* d_out = (float*)d_out_v;

    char* ws = (char*)d_ws;
    size_t off = 0;
    auto alloc = [&](size_t bytes) -> char* {
        char* p = ws + off;
        off += (bytes + 255) & ~(size_t)255;
        return p;
    };
    // ---- zeroed state zone
    u16*   hT = (u16*)alloc((size_t)4 * 1408 * 128 * 2);
    float* cT = (float*)alloc((size_t)4 * 1408 * 128 * 4);
    float* cB = (float*)alloc((size_t)4 * 64 * 512 * 4);
    float* cP = (float*)alloc((size_t)4 * 64 * 512 * 4);
    float* pre4g = (float*)alloc((size_t)200 * 64 * 4 * 4);
    float* pre6g = (float*)alloc((size_t)200 * 64 * 6 * 4);
    unsigned* cnts = (unsigned*)alloc(256);
    u16*   hZ = (u16*)alloc((size_t)4 * 64 * 512 * 2);
    size_t stateBytes = off;
    // ---- recomputed-each-call zone
    u16*   hRB = (u16*)alloc((size_t)200 * 4 * 64 * 512 * 2);
    u16*   hRP = (u16*)alloc((size_t)200 * 4 * 64 * 512 * 2);
    u16*   rnn = (u16*)alloc((size_t)200 * 64 * 640 * 2);
    float* ptraceF = (float*)alloc((size_t)200 * 1408 * 2 * 4);
    u16*   packB = (u16*)alloc(((size_t)128 * 36 * 512 + (size_t)3 * 128 * 32 * 512) * 2);
    u16*   packP = (u16*)alloc(((size_t)128 * 36 * 512 + (size_t)3 * 128 * 32 * 512) * 2);
    u16*   packT = (u16*)alloc((size_t)(128 + 3 * 256) * 512 * 2);
    float* bcB = (float*)alloc((size_t)4 * 2048 * 4);
    float* bcP = (float*)alloc((size_t)4 * 2048 * 4);
    float* bcT = (float*)alloc((size_t)4 * 512 * 4);

    unsigned* barCnt = cnts;
    unsigned* trajCnt = cnts + 32;

    hipMemsetAsync(d_ws, 0, stateBytes, stream);

    auto packLaunch = [&](const float* Wih, int Kih, int Kihp, const float* Whh, int Khh,
                          int N, int remap, u16* dst) {
        long total = (long)(N / 16) * ((Kihp + Khh) / 32) * 64;
        int blocks = (int)((total + 255) / 256);
        k_pack<<<dim3(blocks), dim3(256), 0, stream>>>(Wih, Kih, Kihp, Whh, Khh, N, remap, dst);
    };
    packLaunch(bWih0, 624, 640, bWhh, 512, 2048, 1, packB);
    for (int l = 1; l < 4; ++l)
        packLaunch(bWihL + (size_t)(l - 1) * 2048 * 512, 512, 512,
                   bWhh + (size_t)l * 2048 * 512, 512, 2048, 0,
                   packB + (size_t)128 * 36 * 512 + (size_t)(l - 1) * 128 * 32 * 512);
    packLaunch(pWih0, 624, 640, pWhh, 512, 2048, 1, packP);
    for (int l = 1; l < 4; ++l)
        packLaunch(pWihL + (size_t)(l - 1) * 2048 * 512, 512, 512,
                   pWhh + (size_t)l * 2048 * 512, 512, 2048, 0,
                   packP + (size_t)128 * 36 * 512 + (size_t)(l - 1) * 128 * 32 * 512);
    packLaunch(nullptr, 0, 0, tWhh, 128, 512, 0, packT);
    for (int l = 1; l < 4; ++l)
        packLaunch(tWihL + (size_t)(l - 1) * 512 * 128, 128, 128,
                   tWhh + (size_t)l * 512 * 128, 128, 512, 0,
                   packT + (size_t)128 * 512 + (size_t)(l - 1) * 256 * 512);

    k_bias<<<dim3((18432 + 255) / 256), dim3(256), 0, stream>>>(
        bbih, bbhh, pbih, pbhh, tbih, tbhh, bcB, bcP, bcT);
    k_coords<<<dim3((200 * 64 * 38 + 255) / 256), dim3(256), 0, stream>>>(coords, ptraceF, rnn);
    k_enc<<<dim3(1600), dim3(256), 0, stream>>>(
        ptraceF, stf_w1, stf_b1, stf_w2, stf_b2, stf_w3, stf_b3, rnn);

    k_persist<<<dim3(76), dim3(512), 0, stream>>>(
        rnn, packB, packP, packT, bcB, bcP, bcT,
        hRB, hRP, hZ, cB, cP, hT, cT, tWih0, ptraceF,
        d_out, lin_w, lin_b, lsw, lsb, plw, plb,
        pre4g, pre6g, barCnt, trajCnt);
}